// Round 2
// baseline (359.138 us; speedup 1.0000x reference)
//
#include <hip/hip_runtime.h>
#include <hip/hip_bf16.h>
#include <stdint.h>

// Problem constants: B=2, S=2048, E=1024, H=16, hd=64.
#define SS 2048
#define EE 1024
#define HH 16
#define HD 64

typedef __attribute__((ext_vector_type(8))) short short8;
typedef __attribute__((ext_vector_type(4))) float f32x4;

__device__ __forceinline__ float bf2f(short s) {
  union { uint32_t u; float f; } x;
  x.u = ((uint32_t)(uint16_t)s) << 16;
  return x.f;
}
__device__ __forceinline__ short f2bf(float f) {
  union { float f; uint32_t u; } x; x.f = f;
  uint32_t r = x.u + 0x7fffu + ((x.u >> 16) & 1u);
  return (short)(r >> 16);
}

// C[m][n] = sum_k A[m][k] * Bw[n][k] + bias[n].  A is fp32 or bf16 (TA); Bw/bias fp32.
// MODE 0: fp32 [M,N] out. MODE 1: qkv scatter to bf16 [B,H,S,hd] q/k/v, q scaled by 0.125.
template<int MODE, typename TA>
__global__ __launch_bounds__(256) void gemm_bt(
    const TA* __restrict__ A, const float* __restrict__ Bw,
    const float* __restrict__ bias,
    float* __restrict__ C,
    short* __restrict__ qw, short* __restrict__ kw, short* __restrict__ vw,
    int M, int N, int K)
{
  __shared__ short sA[128*32];
  __shared__ short sB[128*32];
  const int tid = threadIdx.x;
  const int lane = tid & 63;
  const int wv = tid >> 6;
  const int wm = (wv >> 1) * 64;
  const int wn = (wv & 1) * 64;
  const int quad = lane >> 4;
  const int lr = lane & 15;
  const int bm = blockIdx.y * 128;
  const int bn = blockIdx.x * 128;

  f32x4 acc[4][4];
  #pragma unroll
  for (int i = 0; i < 4; ++i)
    #pragma unroll
    for (int j = 0; j < 4; ++j) acc[i][j] = (f32x4){0.f, 0.f, 0.f, 0.f};

  for (int k0 = 0; k0 < K; k0 += 32) {
    __syncthreads();
    // Stage A tile (convert fp32->bf16 if needed)
    if constexpr (sizeof(TA) == 4) {
      #pragma unroll
      for (int it = 0; it < 4; ++it) {
        int c = it * 256 + tid;          // 0..1023 chunks of 4 floats
        int row = c >> 3;                // 0..127
        int ch = (c & 7) * 4;            // 0..28
        float4 va = *(const float4*)&A[(size_t)(bm + row)*K + k0 + ch];
        union { short s[4]; uint2 u; } pk;
        pk.s[0] = f2bf(va.x); pk.s[1] = f2bf(va.y);
        pk.s[2] = f2bf(va.z); pk.s[3] = f2bf(va.w);
        *(uint2*)&sA[row*32 + ch] = pk.u;
      }
    } else {
      #pragma unroll
      for (int it = 0; it < 2; ++it) {
        int c = it * 256 + tid;          // 0..511 chunks of 8 bf16
        int row = c >> 2;                // 0..127
        int ch = (c & 3) * 8;            // 0,8,16,24
        *(uint4*)&sA[row*32 + ch] = *(const uint4*)&A[(size_t)(bm + row)*K + k0 + ch];
      }
    }
    // Stage B tile (always fp32 -> bf16)
    #pragma unroll
    for (int it = 0; it < 4; ++it) {
      int c = it * 256 + tid;
      int row = c >> 3;
      int ch = (c & 7) * 4;
      float4 vb = *(const float4*)&Bw[(size_t)(bn + row)*K + k0 + ch];
      union { short s[4]; uint2 u; } pk;
      pk.s[0] = f2bf(vb.x); pk.s[1] = f2bf(vb.y);
      pk.s[2] = f2bf(vb.z); pk.s[3] = f2bf(vb.w);
      *(uint2*)&sB[row*32 + ch] = pk.u;
    }
    __syncthreads();
    short8 af[4], bfr[4];
    #pragma unroll
    for (int i = 0; i < 4; ++i) af[i] = *(const short8*)&sA[(wm + i*16 + lr)*32 + quad*8];
    #pragma unroll
    for (int j = 0; j < 4; ++j) bfr[j] = *(const short8*)&sB[(wn + j*16 + lr)*32 + quad*8];
    #pragma unroll
    for (int i = 0; i < 4; ++i)
      #pragma unroll
      for (int j = 0; j < 4; ++j)
        acc[i][j] = __builtin_amdgcn_mfma_f32_16x16x32_bf16(af[i], bfr[j], acc[i][j], 0, 0, 0);
  }

  #pragma unroll
  for (int i = 0; i < 4; ++i) {
    int row0 = bm + wm + i*16 + quad*4;
    #pragma unroll
    for (int j = 0; j < 4; ++j) {
      int col = bn + wn + j*16 + lr;
      float bv = bias[col];
      #pragma unroll
      for (int r = 0; r < 4; ++r) {
        float v = acc[i][j][r] + bv;
        int rr = row0 + r;
        if (MODE == 0) {
          C[(size_t)rr * N + col] = v;
        } else {
          int which = col >> 10;        // 0=q 1=k 2=v
          int e = col & 1023;
          int h = e >> 6, d = e & 63;
          int b_ = rr >> 11, s = rr & 2047;   // M = B*S, S=2048
          size_t dst = ((size_t)(b_ * HH + h) * SS + s) * HD + d;
          if (which == 0)      qw[dst] = f2bf(v * 0.125f);  // fold 1/sqrt(hd)
          else if (which == 1) kw[dst] = f2bf(v);
          else                 vw[dst] = f2bf(v);
        }
      }
    }
  }
}

// Flash attention fwd, causal. Q/K/V in [B,H,S,64] bf16. Out -> [B,S,E] bf16.
// Block = 512 threads = 8 waves; q-tile 128 (16 rows/wave); k-tile 32 in LDS.
__global__ __launch_bounds__(512) void attn_kernel(
    const short* __restrict__ Q, const short* __restrict__ K,
    const short* __restrict__ V, short* __restrict__ O)
{
  __shared__ short sK[32*64];    // [k][d]
  __shared__ short sVt[64*32];   // [d][k] transposed for B-operand reads
  __shared__ short sP[8][16*32]; // per-wave P tile (C-layout -> A-layout roundtrip)
  const int tid = threadIdx.x;
  const int lane = tid & 63;
  const int w = tid >> 6;
  const int quad = lane >> 4;
  const int lr = lane & 15;
  const int qt = blockIdx.x & 15;     // S/128 = 16 q-tiles
  const int bh = blockIdx.x >> 4;     // b*16+h
  const int b = bh >> 4, h = bh & 15;
  const short* Qb = Q + (size_t)bh * SS * HD;
  const short* Kb = K + (size_t)bh * SS * HD;
  const short* Vb = V + (size_t)bh * SS * HD;
  const int qrow0 = qt * 128 + w * 16;

  short8 qf[2];
  #pragma unroll
  for (int s = 0; s < 2; ++s)
    qf[s] = *(const short8*)&Qb[(size_t)(qrow0 + lr) * HD + s*32 + quad*8];

  f32x4 o[4];
  #pragma unroll
  for (int jd = 0; jd < 4; ++jd) o[jd] = (f32x4){0.f, 0.f, 0.f, 0.f};
  float m[4], l[4];
  #pragma unroll
  for (int r = 0; r < 4; ++r) { m[r] = -1e30f; l[r] = 0.f; }

  const int kend = qt * 128 + 128;
  for (int kb = 0; kb < kend; kb += 32) {
    __syncthreads();
    if (tid < 256) {                          // waves 0-3 stage K
      int k = tid >> 3, ch = (tid & 7) * 8;
      *(uint4*)&sK[k*64 + ch] = *(const uint4*)&Kb[(size_t)(kb + k) * HD + ch];
    } else {                                  // waves 4-7 stage V transposed
      int t = tid - 256;
      int k = t >> 3, ch = (t & 7) * 8;
      uint4 vv = *(const uint4*)&Vb[(size_t)(kb + k) * HD + ch];
      const short* tp = (const short*)&vv;
      #pragma unroll
      for (int jj = 0; jj < 8; ++jj) sVt[(ch + jj)*32 + k] = tp[jj];
    }
    __syncthreads();
    const bool active = (kb <= qrow0 + 15);   // causal: wave-uniform skip
    if (active) {
      f32x4 sc[2];
      sc[0] = (f32x4){0.f,0.f,0.f,0.f};
      sc[1] = (f32x4){0.f,0.f,0.f,0.f};
      #pragma unroll
      for (int c = 0; c < 2; ++c)
        #pragma unroll
        for (int st = 0; st < 2; ++st) {
          short8 kf = *(const short8*)&sK[(c*16 + lr)*64 + st*32 + quad*8];
          sc[c] = __builtin_amdgcn_mfma_f32_16x16x32_bf16(qf[st], kf, sc[c], 0, 0, 0);
        }
      float tm[4];
      #pragma unroll
      for (int r = 0; r < 4; ++r) {
        int qrow = qrow0 + quad*4 + r;
        #pragma unroll
        for (int c = 0; c < 2; ++c) {
          int krow = kb + c*16 + lr;
          float s_ = sc[c][r];                 // scale folded into Q
          if (krow > qrow) s_ = -1e30f;
          sc[c][r] = s_;
        }
        tm[r] = fmaxf(sc[0][r], sc[1][r]);
      }
      #pragma unroll
      for (int off = 1; off < 16; off <<= 1)
        #pragma unroll
        for (int r = 0; r < 4; ++r) tm[r] = fmaxf(tm[r], __shfl_xor(tm[r], off));
      float al[4], rs[4];
      #pragma unroll
      for (int r = 0; r < 4; ++r) {
        float mn = fmaxf(m[r], tm[r]);
        al[r] = __expf(m[r] - mn);
        m[r] = mn;
        sc[0][r] = __expf(sc[0][r] - mn);
        sc[1][r] = __expf(sc[1][r] - mn);
        rs[r] = sc[0][r] + sc[1][r];
      }
      #pragma unroll
      for (int off = 1; off < 16; off <<= 1)
        #pragma unroll
        for (int r = 0; r < 4; ++r) rs[r] += __shfl_xor(rs[r], off);
      #pragma unroll
      for (int r = 0; r < 4; ++r) l[r] = l[r] * al[r] + rs[r];
      #pragma unroll
      for (int jd = 0; jd < 4; ++jd)
        #pragma unroll
        for (int r = 0; r < 4; ++r) o[jd][r] *= al[r];
      short* sPw = sP[w];
      #pragma unroll
      for (int c = 0; c < 2; ++c)
        #pragma unroll
        for (int r = 0; r < 4; ++r)
          sPw[(quad*4 + r)*32 + c*16 + lr] = f2bf(sc[c][r]);
    }
    __syncthreads();
    if (active) {
      short8 pf = *(const short8*)&sP[w][lr*32 + quad*8];   // A-layout read
      #pragma unroll
      for (int jd = 0; jd < 4; ++jd) {
        short8 vf = *(const short8*)&sVt[(jd*16 + lr)*32 + quad*8];
        o[jd] = __builtin_amdgcn_mfma_f32_16x16x32_bf16(pf, vf, o[jd], 0, 0, 0);
      }
    }
  }

  #pragma unroll
  for (int jd = 0; jd < 4; ++jd)
    #pragma unroll
    for (int r = 0; r < 4; ++r) {
      int qrow = qrow0 + quad*4 + r;
      int d = jd*16 + lr;
      float val = o[jd][r] / l[r];
      O[((size_t)(b * SS + qrow)) * EE + h * HD + d] = f2bf(val);
    }
}

extern "C" void kernel_launch(void* const* d_in, const int* in_sizes, int n_in,
                              void* d_out, int out_size, void* d_ws, size_t ws_size,
                              hipStream_t stream) {
  const float* X     = (const float*)d_in[0];  // [B,S,E] fp32
  const float* W_in  = (const float*)d_in[1];  // [3E,E]  fp32
  const float* b_in  = (const float*)d_in[2];  // [3E]    fp32
  const float* W_out = (const float*)d_in[3];  // [E,E]   fp32
  const float* b_out = (const float*)d_in[4];  // [E]     fp32
  float* out = (float*)d_out;                  // [B,S,E] fp32

  char* ws = (char*)d_ws;                      // 32 MiB used
  short* q_ws = (short*)(ws);
  short* k_ws = (short*)(ws + (size_t)8  * 1024 * 1024);
  short* v_ws = (short*)(ws + (size_t)16 * 1024 * 1024);
  short* attn = (short*)(ws + (size_t)24 * 1024 * 1024);

  const int M = 2 * SS;  // 4096

  // QKV projection: [4096,1024]fp32 x [3072,1024]^T fp32 -> bf16 q/k/v [B,H,S,64]
  gemm_bt<1, float><<<dim3(3 * EE / 128, M / 128), 256, 0, stream>>>(
      X, W_in, b_in, nullptr, q_ws, k_ws, v_ws, M, 3 * EE, EE);

  // Causal flash attention -> attn [B,S,E] bf16
  attn_kernel<<<dim3(2 * HH * (SS / 128)), 512, 0, stream>>>(q_ws, k_ws, v_ws, attn);

  // Output projection: [4096,1024]bf16 x [1024,1024]^T fp32 -> d_out fp32
  gemm_bt<0, short><<<dim3(EE / 128, M / 128), 256, 0, stream>>>(
      attn, W_out, b_out, out, nullptr, nullptr, nullptr, M, EE, EE);
}

// Round 3
// 212.457 us; speedup vs baseline: 1.6904x; 1.6904x over previous
//
#include <hip/hip_runtime.h>
#include <hip/hip_bf16.h>
#include <stdint.h>

// Problem constants: B=2, S=2048, E=1024, H=16, hd=64.
#define SS 2048
#define EE 1024
#define HH 16
#define HD 64

typedef __attribute__((ext_vector_type(8))) short short8;
typedef __attribute__((ext_vector_type(4))) float f32x4;

__device__ __forceinline__ short f2bf(float f) {
  union { float f; uint32_t u; } x; x.f = f;
  uint32_t r = x.u + 0x7fffu + ((x.u >> 16) & 1u);
  return (short)(r >> 16);
}

__device__ __forceinline__ void async_cp16(const void* g, void* l) {
  __builtin_amdgcn_global_load_lds((const __attribute__((address_space(1))) void*)g,
                                   (__attribute__((address_space(3))) void*)l, 16, 0, 0);
}

// ---------------- fp32 -> bf16 pre-convert (X, W_in, W_out) ----------------
#define N4_X  1048576   // 2*2048*1024 / 4
#define N4_W1 786432    // 3072*1024 / 4
#define N4_W2 262144    // 1024*1024 / 4
__global__ __launch_bounds__(256) void cvt_all(
    const float* __restrict__ x, const float* __restrict__ w1,
    const float* __restrict__ w2,
    short* __restrict__ xb, short* __restrict__ w1b, short* __restrict__ w2b)
{
  int i = blockIdx.x * 256 + threadIdx.x;   // 0 .. 2097151
  const float* src; short* dst; int off;
  if (i < N4_X)            { src = x;  dst = xb;  off = i; }
  else if (i < N4_X+N4_W1) { src = w1; dst = w1b; off = i - N4_X; }
  else                     { src = w2; dst = w2b; off = i - N4_X - N4_W1; }
  float4 v = *(const float4*)&src[(size_t)off * 4];
  union { short s[4]; uint2 u; } pk;
  pk.s[0] = f2bf(v.x); pk.s[1] = f2bf(v.y); pk.s[2] = f2bf(v.z); pk.s[3] = f2bf(v.w);
  *(uint2*)&dst[(size_t)off * 4] = pk.u;
}

// ---------------- m97-style bf16 GEMM: C = A * Bw^T + bias ----------------
// MODE 0: fp32 [M,N] out. MODE 1: qkv scatter -> q/k [B,H,S,64], v [B,H,64,S], q*0.125
template<int MODE>
__global__ __launch_bounds__(256) void gemm_lds(
    const short* __restrict__ A, const short* __restrict__ Bw,
    const float* __restrict__ bias,
    float* __restrict__ C,
    short* __restrict__ qw, short* __restrict__ kw, short* __restrict__ vw,
    int M, int N, int K)
{
  __shared__ short sA[128*32];
  __shared__ short sB[128*32];
  const int tid = threadIdx.x;
  const int lane = tid & 63;
  const int wv = tid >> 6;
  const int wm = (wv >> 1) * 64;
  const int wn = (wv & 1) * 64;
  const int quad = lane >> 4;
  const int lr = lane & 15;
  const int bm = blockIdx.y * 128;
  const int bn = blockIdx.x * 128;

  f32x4 acc[4][4];
  #pragma unroll
  for (int i = 0; i < 4; ++i)
    #pragma unroll
    for (int j = 0; j < 4; ++j) acc[i][j] = (f32x4){0.f, 0.f, 0.f, 0.f};

  for (int k0 = 0; k0 < K; k0 += 32) {
    __syncthreads();
    #pragma unroll
    for (int it = 0; it < 2; ++it) {
      int c = it * 256 + wv * 64 + lane;   // chunk id: lane-contiguous within wave
      int row = c >> 2;
      int ch = (c & 3) * 8;
      // wave-uniform LDS base; HW scatters lane i to base + i*16
      async_cp16(&A[(size_t)(bm + row) * K + k0 + ch],
                 (char*)sA + (size_t)(it * 256 + wv * 64) * 16);
      async_cp16(&Bw[(size_t)(bn + row) * K + k0 + ch],
                 (char*)sB + (size_t)(it * 256 + wv * 64) * 16);
    }
    __syncthreads();   // compiler drains vmcnt before barrier
    short8 af[4], bfr[4];
    #pragma unroll
    for (int i = 0; i < 4; ++i) af[i] = *(const short8*)&sA[(wm + i*16 + lr)*32 + quad*8];
    #pragma unroll
    for (int j = 0; j < 4; ++j) bfr[j] = *(const short8*)&sB[(wn + j*16 + lr)*32 + quad*8];
    #pragma unroll
    for (int i = 0; i < 4; ++i)
      #pragma unroll
      for (int j = 0; j < 4; ++j)
        acc[i][j] = __builtin_amdgcn_mfma_f32_16x16x32_bf16(af[i], bfr[j], acc[i][j], 0, 0, 0);
  }

  #pragma unroll
  for (int i = 0; i < 4; ++i) {
    int row0 = bm + wm + i*16 + quad*4;
    #pragma unroll
    for (int j = 0; j < 4; ++j) {
      int col = bn + wn + j*16 + lr;
      float bv = bias[col];
      #pragma unroll
      for (int r = 0; r < 4; ++r) {
        float v = acc[i][j][r] + bv;
        int rr = row0 + r;
        if (MODE == 0) {
          C[(size_t)rr * N + col] = v;
        } else {
          int which = col >> 10;        // 0=q 1=k 2=v
          int e = col & 1023;
          int h = e >> 6, d = e & 63;
          int b_ = rr >> 11, s = rr & 2047;
          if (which == 0)
            qw[((size_t)(b_*HH + h)*SS + s)*HD + d] = f2bf(v * 0.125f);
          else if (which == 1)
            kw[((size_t)(b_*HH + h)*SS + s)*HD + d] = f2bf(v);
          else  // v stored transposed: [B,H,64,S]
            vw[((size_t)(b_*HH + h)*HD + d)*SS + s] = f2bf(v);
        }
      }
    }
  }
}

// ------------- fallback GEMM (fp32 staging convert), round-2 proven -------------
template<int MODE, typename TA>
__global__ __launch_bounds__(256) void gemm_bt(
    const TA* __restrict__ A, const float* __restrict__ Bw,
    const float* __restrict__ bias,
    float* __restrict__ C,
    short* __restrict__ qw, short* __restrict__ kw, short* __restrict__ vw,
    int M, int N, int K)
{
  __shared__ short sA[128*32];
  __shared__ short sB[128*32];
  const int tid = threadIdx.x;
  const int lane = tid & 63;
  const int wv = tid >> 6;
  const int wm = (wv >> 1) * 64;
  const int wn = (wv & 1) * 64;
  const int quad = lane >> 4;
  const int lr = lane & 15;
  const int bm = blockIdx.y * 128;
  const int bn = blockIdx.x * 128;

  f32x4 acc[4][4];
  #pragma unroll
  for (int i = 0; i < 4; ++i)
    #pragma unroll
    for (int j = 0; j < 4; ++j) acc[i][j] = (f32x4){0.f, 0.f, 0.f, 0.f};

  for (int k0 = 0; k0 < K; k0 += 32) {
    __syncthreads();
    if constexpr (sizeof(TA) == 4) {
      #pragma unroll
      for (int it = 0; it < 4; ++it) {
        int c = it * 256 + tid;
        int row = c >> 3, ch = (c & 7) * 4;
        float4 va = *(const float4*)&A[(size_t)(bm + row)*K + k0 + ch];
        union { short s[4]; uint2 u; } pk;
        pk.s[0]=f2bf(va.x); pk.s[1]=f2bf(va.y); pk.s[2]=f2bf(va.z); pk.s[3]=f2bf(va.w);
        *(uint2*)&sA[row*32 + ch] = pk.u;
      }
    } else {
      #pragma unroll
      for (int it = 0; it < 2; ++it) {
        int c = it * 256 + tid;
        int row = c >> 2, ch = (c & 3) * 8;
        *(uint4*)&sA[row*32 + ch] = *(const uint4*)&A[(size_t)(bm + row)*K + k0 + ch];
      }
    }
    #pragma unroll
    for (int it = 0; it < 4; ++it) {
      int c = it * 256 + tid;
      int row = c >> 3, ch = (c & 7) * 4;
      float4 vb = *(const float4*)&Bw[(size_t)(bn + row)*K + k0 + ch];
      union { short s[4]; uint2 u; } pk;
      pk.s[0]=f2bf(vb.x); pk.s[1]=f2bf(vb.y); pk.s[2]=f2bf(vb.z); pk.s[3]=f2bf(vb.w);
      *(uint2*)&sB[row*32 + ch] = pk.u;
    }
    __syncthreads();
    short8 af[4], bfr[4];
    #pragma unroll
    for (int i = 0; i < 4; ++i) af[i] = *(const short8*)&sA[(wm + i*16 + lr)*32 + quad*8];
    #pragma unroll
    for (int j = 0; j < 4; ++j) bfr[j] = *(const short8*)&sB[(wn + j*16 + lr)*32 + quad*8];
    #pragma unroll
    for (int i = 0; i < 4; ++i)
      #pragma unroll
      for (int j = 0; j < 4; ++j)
        acc[i][j] = __builtin_amdgcn_mfma_f32_16x16x32_bf16(af[i], bfr[j], acc[i][j], 0, 0, 0);
  }

  #pragma unroll
  for (int i = 0; i < 4; ++i) {
    int row0 = bm + wm + i*16 + quad*4;
    #pragma unroll
    for (int j = 0; j < 4; ++j) {
      int col = bn + wn + j*16 + lr;
      float bv = bias[col];
      #pragma unroll
      for (int r = 0; r < 4; ++r) {
        float v = acc[i][j][r] + bv;
        int rr = row0 + r;
        if (MODE == 0) {
          C[(size_t)rr * N + col] = v;
        } else {
          int which = col >> 10;
          int e = col & 1023;
          int h = e >> 6, d = e & 63;
          int b_ = rr >> 11, s = rr & 2047;
          if (which == 0)
            qw[((size_t)(b_*HH + h)*SS + s)*HD + d] = f2bf(v * 0.125f);
          else if (which == 1)
            kw[((size_t)(b_*HH + h)*SS + s)*HD + d] = f2bf(v);
          else
            vw[((size_t)(b_*HH + h)*HD + d)*SS + s] = f2bf(v);
        }
      }
    }
  }
}

// ---------------- causal flash attention, Br=Bc=128 ----------------
// Q,K: [B,H,S,64] bf16; Vt: [B,H,64,S] bf16 (pre-transposed); O: [B,S,E] bf16.
// 512 threads = 8 waves; wave owns 16 q-rows; all waves active every k-iter.
__global__ __launch_bounds__(512) void attn_kernel(
    const short* __restrict__ Q, const short* __restrict__ K,
    const short* __restrict__ Vt, short* __restrict__ O)
{
  __shared__ short sK[128*72];     // [k][d], stride 72 (pad 8) -> 2-way max
  __shared__ short sVt[64*136];    // [d][s], stride 136 (pad 8)
  __shared__ short sP[8][16*72];   // per-wave P half-tile (16 x 64, stride 72)
  const int tid = threadIdx.x;
  const int lane = tid & 63;
  const int w = tid >> 6;
  const int quad = lane >> 4;
  const int lr = lane & 15;
  const int qt = 15 - (blockIdx.x >> 5);  // long blocks dispatched first
  const int bh = blockIdx.x & 31;
  const int b = bh >> 4, h = bh & 15;
  const short* Qb = Q  + (size_t)bh * SS * HD;
  const short* Kb = K  + (size_t)bh * SS * HD;
  const short* Vb = Vt + (size_t)bh * HD * SS;
  const int qrow0 = qt * 128 + w * 16;

  short8 qf[2];
  #pragma unroll
  for (int s = 0; s < 2; ++s)
    qf[s] = *(const short8*)&Qb[(size_t)(qrow0 + lr) * HD + s*32 + quad*8];

  f32x4 o[4];
  #pragma unroll
  for (int jd = 0; jd < 4; ++jd) o[jd] = (f32x4){0.f, 0.f, 0.f, 0.f};
  float m[4], l[4];
  #pragma unroll
  for (int r = 0; r < 4; ++r) { m[r] = -1e30f; l[r] = 0.f; }

  for (int kb = 0; kb <= qt * 128; kb += 128) {
    __syncthreads();
    #pragma unroll
    for (int ps = 0; ps < 2; ++ps) {        // K tile: 128 rows x 64 d
      int t = ps * 512 + tid;
      int row = t >> 3, ch = (t & 7) * 8;
      *(uint4*)&sK[row*72 + ch] = *(const uint4*)&Kb[(size_t)(kb + row)*HD + ch];
    }
    #pragma unroll
    for (int ps = 0; ps < 2; ++ps) {        // V^T tile: 64 rows x 128 s
      int t = ps * 512 + tid;
      int row = t >> 4, ch = (t & 15) * 8;
      *(uint4*)&sVt[row*136 + ch] = *(const uint4*)&Vb[(size_t)row*SS + kb + ch];
    }
    __syncthreads();

    f32x4 sc[8];
    #pragma unroll
    for (int c = 0; c < 8; ++c) sc[c] = (f32x4){0.f,0.f,0.f,0.f};
    #pragma unroll
    for (int c = 0; c < 8; ++c)
      #pragma unroll
      for (int st = 0; st < 2; ++st) {
        short8 kf = *(const short8*)&sK[(c*16 + lr)*72 + st*32 + quad*8];
        sc[c] = __builtin_amdgcn_mfma_f32_16x16x32_bf16(qf[st], kf, sc[c], 0, 0, 0);
      }

    if (kb + 128 > qrow0) {                 // only the diagonal iteration masks
      #pragma unroll
      for (int r = 0; r < 4; ++r) {
        int qrow = qrow0 + quad*4 + r;
        #pragma unroll
        for (int c = 0; c < 8; ++c) {
          int krow = kb + c*16 + lr;
          if (krow > qrow) sc[c][r] = -1e30f;
        }
      }
    }

    float tm[4];
    #pragma unroll
    for (int r = 0; r < 4; ++r) {
      tm[r] = sc[0][r];
      #pragma unroll
      for (int c = 1; c < 8; ++c) tm[r] = fmaxf(tm[r], sc[c][r]);
    }
    #pragma unroll
    for (int off = 1; off < 16; off <<= 1)
      #pragma unroll
      for (int r = 0; r < 4; ++r) tm[r] = fmaxf(tm[r], __shfl_xor(tm[r], off));

    float al[4], rs[4];
    #pragma unroll
    for (int r = 0; r < 4; ++r) {
      float mn = fmaxf(m[r], tm[r]);
      al[r] = __expf(m[r] - mn);
      m[r] = mn;
      rs[r] = 0.f;
      #pragma unroll
      for (int c = 0; c < 8; ++c) {
        sc[c][r] = __expf(sc[c][r] - mn);
        rs[r] += sc[c][r];
      }
    }
    #pragma unroll
    for (int off = 1; off < 16; off <<= 1)
      #pragma unroll
      for (int r = 0; r < 4; ++r) rs[r] += __shfl_xor(rs[r], off);
    #pragma unroll
    for (int r = 0; r < 4; ++r) l[r] = l[r] * al[r] + rs[r];
    #pragma unroll
    for (int jd = 0; jd < 4; ++jd)
      #pragma unroll
      for (int r = 0; r < 4; ++r) o[jd][r] *= al[r];

    // PV in two 64-col halves; sP is per-wave (DS ops in-order -> no barrier)
    short* sPw = sP[w];
    #pragma unroll
    for (int hf = 0; hf < 2; ++hf) {
      #pragma unroll
      for (int c2 = 0; c2 < 4; ++c2)
        #pragma unroll
        for (int r = 0; r < 4; ++r)
          sPw[(quad*4 + r)*72 + c2*16 + lr] = f2bf(sc[hf*4 + c2][r]);
      short8 pf[2];
      #pragma unroll
      for (int kk = 0; kk < 2; ++kk)
        pf[kk] = *(const short8*)&sPw[lr*72 + kk*32 + quad*8];
      #pragma unroll
      for (int jd = 0; jd < 4; ++jd)
        #pragma unroll
        for (int kk = 0; kk < 2; ++kk) {
          short8 vf = *(const short8*)&sVt[(jd*16 + lr)*136 + hf*64 + kk*32 + quad*8];
          o[jd] = __builtin_amdgcn_mfma_f32_16x16x32_bf16(pf[kk], vf, o[jd], 0, 0, 0);
        }
    }
  }

  #pragma unroll
  for (int jd = 0; jd < 4; ++jd)
    #pragma unroll
    for (int r = 0; r < 4; ++r) {
      int qrow = qrow0 + quad*4 + r;
      int d = jd*16 + lr;
      O[((size_t)(b * SS + qrow)) * EE + h * HD + d] = f2bf(o[jd][r] / l[r]);
    }
}

extern "C" void kernel_launch(void* const* d_in, const int* in_sizes, int n_in,
                              void* d_out, int out_size, void* d_ws, size_t ws_size,
                              hipStream_t stream) {
  const float* X     = (const float*)d_in[0];
  const float* W_in  = (const float*)d_in[1];
  const float* b_in  = (const float*)d_in[2];
  const float* W_out = (const float*)d_in[3];
  const float* b_out = (const float*)d_in[4];
  float* out = (float*)d_out;

  char* ws = (char*)d_ws;
  const size_t MB = 1024 * 1024;
  const int M = 2 * SS;  // 4096

  if (ws_size >= 48 * MB) {
    short* Xb   = (short*)(ws);
    short* Wb1  = (short*)(ws + 8  * MB);
    short* Wb2  = (short*)(ws + 14 * MB);
    short* q_ws = (short*)(ws + 16 * MB);
    short* k_ws = (short*)(ws + 24 * MB);
    short* v_ws = (short*)(ws + 32 * MB);
    short* attn = (short*)(ws + 40 * MB);

    cvt_all<<<8192, 256, 0, stream>>>(X, W_in, W_out, Xb, Wb1, Wb2);
    gemm_lds<1><<<dim3(24, 32), 256, 0, stream>>>(
        Xb, Wb1, b_in, nullptr, q_ws, k_ws, v_ws, M, 3 * EE, EE);
    attn_kernel<<<dim3(512), 512, 0, stream>>>(q_ws, k_ws, v_ws, attn);
    gemm_lds<0><<<dim3(8, 32), 256, 0, stream>>>(
        attn, Wb2, b_out, out, nullptr, nullptr, nullptr, M, EE, EE);
  } else {
    short* q_ws = (short*)(ws);
    short* k_ws = (short*)(ws + 8  * MB);
    short* v_ws = (short*)(ws + 16 * MB);
    short* attn = (short*)(ws + 24 * MB);

    gemm_bt<1, float><<<dim3(24, 32), 256, 0, stream>>>(
        X, W_in, b_in, nullptr, q_ws, k_ws, v_ws, M, 3 * EE, EE);
    attn_kernel<<<dim3(512), 512, 0, stream>>>(q_ws, k_ws, v_ws, attn);
    gemm_bt<0, short><<<dim3(8, 32), 256, 0, stream>>>(
        attn, W_out, b_out, out, nullptr, nullptr, nullptr, M, EE, EE);
  }
}